// Round 12
// baseline (99.839 us; speedup 1.0000x reference)
//
#include <hip/hip_runtime.h>
#include <hip/hip_bf16.h>

#define BATCH 16384
#define DIM   512
#define NPG   64
#define NPAIR 4096
#define NA    128

typedef float f32x4 __attribute__((ext_vector_type(4)));
typedef short s16x8 __attribute__((ext_vector_type(8)));
typedef unsigned short u16;

static __device__ __forceinline__ u16 f2bf(float f) {
    union { float f; unsigned u; } v; v.f = f;
    unsigned r = (v.u + 0x7FFFu + ((v.u >> 16) & 1u)) >> 16;
    return (u16)r;
}

// kA: A[j][d] = proto[j] . W[d][koff:koff+512], K-split x2 across lane pairs.
__global__ __launch_bounds__(256) void kA_mixA(const float* __restrict__ proto,
                                               const float* __restrict__ W,
                                               float* __restrict__ Af,
                                               u16* __restrict__ Ab) {
    int gid = blockIdx.x * 256 + threadIdx.x;
    int h = gid & 1;
    int j = (gid >> 1) & 127;
    int d = gid >> 8;
    int koff = (j < NPG ? 0 : DIM) + h * (DIM / 2);
    const float4* pr = (const float4*)(proto + j * DIM + h * (DIM / 2));
    const float4* wr = (const float4*)(W + d * (2 * DIM) + koff);
    float a0 = 0.f, a1 = 0.f, a2 = 0.f, a3 = 0.f;
#pragma unroll 4
    for (int k4 = 0; k4 < DIM / 8; ++k4) {
        float4 p = pr[k4], w = wr[k4];
        a0 += p.x * w.x; a1 += p.y * w.y; a2 += p.z * w.z; a3 += p.w * w.w;
    }
    float a = (a0 + a1) + (a2 + a3);
    a += __shfl_xor(a, 1);
    if (h == 0) {
        Af[j * DIM + d] = a;
        Ab[j * DIM + d] = f2bf(a);
    }
}

// k2: pp[j*64+l] = || A[j] + A[64+l] + b ||^2   (one wave per pair)
__global__ __launch_bounds__(256) void k2_pp(const float* __restrict__ Af,
                                             const float* __restrict__ bm,
                                             float* __restrict__ pp) {
    int wave = (blockIdx.x * blockDim.x + threadIdx.x) >> 6;  // 4096 waves
    int lane = threadIdx.x & 63;
    int j = wave >> 6, l = wave & 63;
    const float4* r0 = (const float4*)(Af + j * DIM);
    const float4* r1 = (const float4*)(Af + (NPG + l) * DIM);
    const float4* bb = (const float4*)bm;
    float acc = 0.f;
#pragma unroll
    for (int i = 0; i < 2; ++i) {
        int idx = lane * 2 + i;
        float4 v0 = r0[idx], v1 = r1[idx], vb = bb[idx];
        float s;
        s = v0.x + v1.x + vb.x; acc += s * s;
        s = v0.y + v1.y + vb.y; acc += s * s;
        s = v0.z + v1.z + vb.z; acc += s * s;
        s = v0.w + v1.w + vb.w; acc += s * s;
    }
#pragma unroll
    for (int off = 32; off > 0; off >>= 1) acc += __shfl_xor(acc, off);
    if (lane == 0) pp[wave] = acc;
}

// kFE: fused GEMM+epilogue, DOUBLE-SLAB pipeline. 512 blocks x 512 threads,
// 32 rows/block = two 16-row slabs (exact kFD slab geometry; Ab traffic
// unchanged). Slab-1 x-loads issued BEFORE slab-0's store stream so HBM read
// latency + stage/MFMA of slab 1 hide under the 256 KB store of slab 0.
__global__ __launch_bounds__(512) void kFE(const float* __restrict__ x,
                                           const u16* __restrict__ Ab,
                                           const float* __restrict__ bm,
                                           const float* __restrict__ pp,
                                           float* __restrict__ out) {
    __shared__ u16   xsb[2][16 * 512];   // 2 x 16 KB swizzled bf16 slabs
    __shared__ float Ut[2][16][NA];      // 2 x 8 KB
    __shared__ float xxs[2][16], ws2[2][16];
    __shared__ float rbl[2][16];
    int t = threadIdx.x;
    int lane = t & 63;
    int w = t >> 6;
    int m0 = blockIdx.x * 32;

    int row = t >> 5;            // 0..15 (32 threads per row)
    int c0 = (t & 31) * 4;
    int r = lane & 15, g = lane >> 4;

    // ---- load bm (shared across slabs) + slab-0 x + ISSUE slab-1 x early
    float4 bmv[4], v0[4], v1[4];
    {
        const float* xr0 = x + (size_t)(m0 + row) * DIM;
        const float* xr1 = x + (size_t)(m0 + 16 + row) * DIM;
#pragma unroll
        for (int i = 0; i < 4; ++i) {
            bmv[i] = *(const float4*)(bm + c0 + i * 128);
            v0[i]  = *(const float4*)(xr0 + c0 + i * 128);
            v1[i]  = *(const float4*)(xr1 + c0 + i * 128);
        }
    }

#pragma unroll
    for (int s = 0; s < 2; ++s) {
        // ---- stage slab s: rb partials + swizzled ds_write
        {
            float xx = 0.f, wdot = 0.f;
#pragma unroll
            for (int i = 0; i < 4; ++i) {
                float4 v = (s == 0) ? v0[i] : v1[i];
                float4 b = bmv[i];
                int col = c0 + i * 128;
                xx   += v.x * v.x + v.y * v.y + v.z * v.z + v.w * v.w;
                wdot += v.x * b.x + v.y * b.y + v.z * b.z + v.w * b.w;
                ushort4 hv;
                hv.x = f2bf(v.x); hv.y = f2bf(v.y); hv.z = f2bf(v.z); hv.w = f2bf(v.w);
                int byte = (row * 1024 + col * 2) ^ ((row & 7) << 4);
                *(ushort4*)((char*)xsb[s] + byte) = hv;
            }
#pragma unroll
            for (int off = 16; off > 0; off >>= 1) {
                xx   += __shfl_xor(xx, off);
                wdot += __shfl_xor(wdot, off);
            }
            if ((t & 31) == 0) { xxs[s][row] = xx; ws2[s][row] = wdot; }
        }
        __syncthreads();
        if (t < 16) rbl[s][t] = xxs[s][t] - 2.0f * ws2[s][t];

        // ---- MFMA slab s: wave w owns col-tile w
        {
            f32x4 acc = (f32x4){0.f, 0.f, 0.f, 0.f};
            const u16* brow = Ab + (size_t)(w * 16 + r) * DIM;
#pragma unroll
            for (int k0 = 0; k0 < 16; ++k0) {
                int byte = (r * 1024 + k0 * 64 + g * 16) ^ ((r & 7) << 4);
                s16x8 af = *(const s16x8*)((const char*)xsb[s] + byte);
                s16x8 bf = *(const s16x8*)(brow + k0 * 32 + g * 8);
                acc = __builtin_amdgcn_mfma_f32_16x16x32_bf16(af, bf, acc, 0, 0, 0);
            }
            // C/D: col = lane&15 -> A-row (w*16+r), row = g*4+reg -> x-row
#pragma unroll
            for (int rr = 0; rr < 4; ++rr)
                Ut[s][g * 4 + rr][w * 16 + r] = acc[rr];
        }
        __syncthreads();

        // ---- store slab s: wave w streams rows {2w, 2w+1}
        // (slab-1 x-loads, issued pre-loop, land under slab-0's store stream)
        {
            int l4 = (lane & 15) * 4;
#pragma unroll
            for (int rl = 0; rl < 2; ++rl) {
                int rw = w * 2 + rl;
                float base0 = rbl[s][rw];
                const float* Ur = Ut[s][rw];
                float4 v4 = *(const float4*)(Ur + NPG + l4);   // loop-invariant
                float cc0 = -2.0f * v4.x, cc1 = -2.0f * v4.y;
                float cc2 = -2.0f * v4.z, cc3 = -2.0f * v4.w;
                float* orow = out + (size_t)(m0 + s * 16 + rw) * NPAIR;
#pragma unroll
                for (int i = 0; i < 16; ++i) {
                    int idx = (i * 64 + lane) * 4;
                    int j = idx >> 6;
                    float sv = base0 - 2.0f * Ur[j];
                    float4 p4 = *(const float4*)(pp + idx);
                    float4 o;
                    o.x = sv + p4.x + cc0;
                    o.y = sv + p4.y + cc1;
                    o.z = sv + p4.z + cc2;
                    o.w = sv + p4.w + cc3;
                    *(float4*)(orow + idx) = o;
                }
            }
        }
        if (s == 0) __syncthreads();   // xsb[1]/Ut[1] writes begin next iter
    }
}

extern "C" void kernel_launch(void* const* d_in, const int* in_sizes, int n_in,
                              void* d_out, int out_size, void* d_ws, size_t ws_size,
                              hipStream_t stream) {
    const float* x     = (const float*)d_in[0];   // [16384, 512]
    const float* proto = (const float*)d_in[1];   // [2, 64, 512] -> flat [128, 512]
    const float* Wmix  = (const float*)d_in[2];   // [512, 1024]
    const float* bmix  = (const float*)d_in[3];   // [512]
    float* out = (float*)d_out;

    float* ws = (float*)d_ws;
    float* Af = ws;                         // 65536 f32
    float* pp = ws + 65536;                 // 4096 f32
    u16*   Ab = (u16*)(ws + 65536 + 4096);  // 65536 bf16

    kA_mixA<<<512, 256, 0, stream>>>(proto, Wmix, Af, Ab);
    k2_pp  <<<1024, 256, 0, stream>>>(Af, bmix, pp);
    kFE    <<<512, 512, 0, stream>>>(x, Ab, bmix, pp, out);
}

// Round 13
// 92.817 us; speedup vs baseline: 1.0756x; 1.0756x over previous
//
#include <hip/hip_runtime.h>
#include <hip/hip_bf16.h>

#define BATCH 16384
#define DIM   512
#define NPG   64
#define NPAIR 4096
#define NA    128

typedef float f32x4 __attribute__((ext_vector_type(4)));
typedef short s16x8 __attribute__((ext_vector_type(8)));
typedef unsigned short u16;

static __device__ __forceinline__ u16 f2bf(float f) {
    union { float f; unsigned u; } v; v.f = f;
    unsigned r = (v.u + 0x7FFFu + ((v.u >> 16) & 1u)) >> 16;
    return (u16)r;
}

// kA: A[j][d] = proto[j] . W[d][koff:koff+512], K-split x2 across lane pairs.
__global__ __launch_bounds__(256) void kA_mixA(const float* __restrict__ proto,
                                               const float* __restrict__ W,
                                               float* __restrict__ Af,
                                               u16* __restrict__ Ab) {
    int gid = blockIdx.x * 256 + threadIdx.x;
    int h = gid & 1;
    int j = (gid >> 1) & 127;
    int d = gid >> 8;
    int koff = (j < NPG ? 0 : DIM) + h * (DIM / 2);
    const float4* pr = (const float4*)(proto + j * DIM + h * (DIM / 2));
    const float4* wr = (const float4*)(W + d * (2 * DIM) + koff);
    float a0 = 0.f, a1 = 0.f, a2 = 0.f, a3 = 0.f;
#pragma unroll 4
    for (int k4 = 0; k4 < DIM / 8; ++k4) {
        float4 p = pr[k4], w = wr[k4];
        a0 += p.x * w.x; a1 += p.y * w.y; a2 += p.z * w.z; a3 += p.w * w.w;
    }
    float a = (a0 + a1) + (a2 + a3);
    a += __shfl_xor(a, 1);
    if (h == 0) {
        Af[j * DIM + d] = a;
        Ab[j * DIM + d] = f2bf(a);
    }
}

// k2: pp[j*64+l] = || A[j] + A[64+l] + b ||^2   (one wave per pair)
__global__ __launch_bounds__(256) void k2_pp(const float* __restrict__ Af,
                                             const float* __restrict__ bm,
                                             float* __restrict__ pp) {
    int wave = (blockIdx.x * blockDim.x + threadIdx.x) >> 6;  // 4096 waves
    int lane = threadIdx.x & 63;
    int j = wave >> 6, l = wave & 63;
    const float4* r0 = (const float4*)(Af + j * DIM);
    const float4* r1 = (const float4*)(Af + (NPG + l) * DIM);
    const float4* bb = (const float4*)bm;
    float acc = 0.f;
#pragma unroll
    for (int i = 0; i < 2; ++i) {
        int idx = lane * 2 + i;
        float4 v0 = r0[idx], v1 = r1[idx], vb = bb[idx];
        float s;
        s = v0.x + v1.x + vb.x; acc += s * s;
        s = v0.y + v1.y + vb.y; acc += s * s;
        s = v0.z + v1.z + vb.z; acc += s * s;
        s = v0.w + v1.w + vb.w; acc += s * s;
    }
#pragma unroll
    for (int off = 32; off > 0; off >>= 1) acc += __shfl_xor(acc, off);
    if (lane == 0) pp[wave] = acc;
}

// kFD: fused kB+kC at proven 16-row slab geometry (measured best: 92.57 us).
// 1024 blocks x 512 threads. Phase1: stage x bf16 swizzled + rb -> LDS.
// Phase2: MFMA, wave w owns col-tile w, U-tile -> LDS. Phase3: epilogue,
// wave w streams rows {2w, 2w+1}; U/rb from LDS, pp from L2.
// U never touches HBM; Ab traffic 128 MB (L2-resident).
__global__ __launch_bounds__(512) void kFD(const float* __restrict__ x,
                                           const u16* __restrict__ Ab,
                                           const float* __restrict__ bm,
                                           const float* __restrict__ pp,
                                           float* __restrict__ out) {
    __shared__ u16   xsb[16 * 512];    // 16 KB swizzled bf16 slab
    __shared__ float Ut[16][NA];       // 8 KB
    __shared__ float xxs[16], ws2[16];
    __shared__ float rbl[16];
    int t = threadIdx.x;
    int lane = t & 63;
    int w = t >> 6;
    int m0 = blockIdx.x * 16;

    // ---- phase 1: staging + rb
    {
        int row = t >> 5;
        int c0 = (t & 31) * 4;
        const float* xrow = x + (size_t)(m0 + row) * DIM;
        float xx = 0.f, wdot = 0.f;
#pragma unroll
        for (int i = 0; i < 4; ++i) {
            int col = c0 + i * 128;
            float4 v = *(const float4*)(xrow + col);
            float4 b = *(const float4*)(bm + col);
            xx   += v.x * v.x + v.y * v.y + v.z * v.z + v.w * v.w;
            wdot += v.x * b.x + v.y * b.y + v.z * b.z + v.w * b.w;
            ushort4 hv;
            hv.x = f2bf(v.x); hv.y = f2bf(v.y); hv.z = f2bf(v.z); hv.w = f2bf(v.w);
            int byte = (row * 1024 + col * 2) ^ ((row & 7) << 4);
            *(ushort4*)((char*)xsb + byte) = hv;
        }
#pragma unroll
        for (int off = 16; off > 0; off >>= 1) {
            xx   += __shfl_xor(xx, off);
            wdot += __shfl_xor(wdot, off);
        }
        if ((t & 31) == 0) { xxs[row] = xx; ws2[row] = wdot; }
    }
    __syncthreads();
    if (t < 16) rbl[t] = xxs[t] - 2.0f * ws2[t];

    // ---- phase 2: MFMA (dest = LDS)
    {
        int r = lane & 15, g = lane >> 4;
        int ct = w;
        f32x4 acc = (f32x4){0.f, 0.f, 0.f, 0.f};
        const u16* brow = Ab + (size_t)(ct * 16 + r) * DIM;
#pragma unroll
        for (int k0 = 0; k0 < 16; ++k0) {
            int byte = (r * 1024 + k0 * 64 + g * 16) ^ ((r & 7) << 4);
            s16x8 af = *(const s16x8*)((const char*)xsb + byte);
            s16x8 bf = *(const s16x8*)(brow + k0 * 32 + g * 8);
            acc = __builtin_amdgcn_mfma_f32_16x16x32_bf16(af, bf, acc, 0, 0, 0);
        }
        // C/D: col = lane&15 -> A-row (ct*16+r), row = g*4+reg -> x-row
#pragma unroll
        for (int rr = 0; rr < 4; ++rr)
            Ut[g * 4 + rr][ct * 16 + r] = acc[rr];
    }
    __syncthreads();

    // ---- phase 3: epilogue. Wave w streams rows {2w, 2w+1}.
    {
        int l4 = (lane & 15) * 4;
#pragma unroll
        for (int rl = 0; rl < 2; ++rl) {
            int row = w * 2 + rl;
            float base0 = rbl[row];
            const float* Ur = Ut[row];
            float4 v4 = *(const float4*)(Ur + NPG + l4);   // loop-invariant
            float c0 = -2.0f * v4.x, c1 = -2.0f * v4.y;
            float c2 = -2.0f * v4.z, c3 = -2.0f * v4.w;
            float* orow = out + (size_t)(m0 + row) * NPAIR;
#pragma unroll
            for (int i = 0; i < 16; ++i) {
                int idx = (i * 64 + lane) * 4;
                int j = idx >> 6;
                float s = base0 - 2.0f * Ur[j];
                float4 p4 = *(const float4*)(pp + idx);
                float4 o;
                o.x = s + p4.x + c0;
                o.y = s + p4.y + c1;
                o.z = s + p4.z + c2;
                o.w = s + p4.w + c3;
                *(float4*)(orow + idx) = o;
            }
        }
    }
}

extern "C" void kernel_launch(void* const* d_in, const int* in_sizes, int n_in,
                              void* d_out, int out_size, void* d_ws, size_t ws_size,
                              hipStream_t stream) {
    const float* x     = (const float*)d_in[0];   // [16384, 512]
    const float* proto = (const float*)d_in[1];   // [2, 64, 512] -> flat [128, 512]
    const float* Wmix  = (const float*)d_in[2];   // [512, 1024]
    const float* bmix  = (const float*)d_in[3];   // [512]
    float* out = (float*)d_out;

    float* ws = (float*)d_ws;
    float* Af = ws;                         // 65536 f32
    float* pp = ws + 65536;                 // 4096 f32
    u16*   Ab = (u16*)(ws + 65536 + 4096);  // 65536 bf16

    kA_mixA<<<512, 256, 0, stream>>>(proto, Wmix, Af, Ab);
    k2_pp  <<<1024, 256, 0, stream>>>(Af, bmix, pp);
    kFD    <<<1024, 512, 0, stream>>>(x, Ab, bmix, pp, out);
}